// Round 4
// baseline (463.754 us; speedup 1.0000x reference)
//
#include <hip/hip_runtime.h>
#include <math.h>

namespace {
constexpr int CDIM   = 128;
constexpr int KCODES = 1024;
constexpr int HWSZ   = 4096;   // 64*64
constexpr int BATCH  = 16;
constexpr int NPOS   = BATCH * HWSZ;            // 65536
constexpr int P      = 64;                      // positions per block
constexpr int TK     = 128;                     // codes per LDS tile
constexpr int NTILES = KCODES / TK;             // 8
constexpr size_t QELEMS   = (size_t)BATCH * CDIM * HWSZ;   // 8388608
constexpr size_t IDX_OFF  = QELEMS;                        // float32 elements
constexpr size_t LOSS_OFF = IDX_OFF + (size_t)NPOS;        // 8454144
constexpr size_t PERP_OFF = LOSS_OFF + 1;
// d_ws float-element offsets
constexpr int WS_C2   = 0;      // [0,1024)   float ||c_k||^2 (numpy-bit-exact)
constexpr int WS_HIST = 1024;   // [1024,2048) uint  usage counts
constexpr int WS_LOSS = 2048;   // [2048]     float sum ||z-q||^2
constexpr float INV_TOTAL = 1.0f / (float)QELEMS;
constexpr float INV_NPOS  = 1.0f / (float)NPOS;
}

// Bit-exact replica of numpy pairwise_sum for n=128 contiguous float32 applied
// to elementwise squares: 8 accumulator chains (stride 8), sequential within a
// chain, combined ((r0+r1)+(r2+r3))+((r4+r5)+(r6+r7)). __f*_rn forbids fma
// contraction (numpy multiplies into a temp, then adds — never fused).
__device__ __forceinline__ float np_sumsq_128(const float* v) {
    float r[8];
    #pragma unroll
    for (int j = 0; j < 8; ++j) r[j] = __fmul_rn(v[j], v[j]);
    #pragma unroll
    for (int i = 8; i < 128; i += 8) {
        #pragma unroll
        for (int j = 0; j < 8; ++j)
            r[j] = __fadd_rn(r[j], __fmul_rn(v[i + j], v[i + j]));
    }
    const float s01 = __fadd_rn(r[0], r[1]);
    const float s23 = __fadd_rn(r[2], r[3]);
    const float s45 = __fadd_rn(r[4], r[5]);
    const float s67 = __fadd_rn(r[6], r[7]);
    return __fadd_rn(__fadd_rn(s01, s23), __fadd_rn(s45, s67));
}

// ---- pass 0: codebook norms (numpy-bit-exact) + zero accumulators ----------
__global__ __launch_bounds__(256) void vq_prep(const float* __restrict__ cb,
                                               float* __restrict__ ws) {
    const int k = blockIdx.x * 256 + threadIdx.x;   // 0..1023
    const float* row = cb + (size_t)k * CDIM;
    float rr[CDIM];
    #pragma unroll
    for (int c = 0; c < CDIM; ++c) rr[c] = row[c];
    ws[WS_C2 + k] = np_sumsq_128(rr);
    ((unsigned int*)ws)[WS_HIST + k] = 0u;
    if (k == 0) ws[WS_LOSS] = 0.0f;
}

// ---- pass 1: register-blocked GEMM-style argmin -----------------------------
// Round 3 analysis: R2->R3 doubled waves/SIMD but VALUBusy moved only 50->55%
// -> binding resource is the SHARED per-CU LDS pipe (12 DS insts / 64 FMA x 8
// waves ~ 430 cy DS vs 256 cy VALU). Fix: thread tile 4 pos x 8 codes -> 12 DS
// per 128 FMA (halved); 1 wave/SIMD is fine (R3 proved wave-2 adds ~nothing).
// Code-read bank math: 4 cgroups/wave, rows 8 apart, row stride 128 floats ->
// all 4 addrs on same banks (4-way, 1.58x; padding can't fix since any 16B-
// aligned stride x8 = 0 mod 32). Fix: XOR-swizzle tile at float4 granularity
// (f' = f ^ cg) on write and read -> 4 distinct bank quads, conflict-free.
// 106KB LDS -> 1 block/CU, so tile staging hides via T14 reg-staging: issue
// tile t+1 global loads (L2-hot codebook) before computing tile t.
// Bit-exactness: per (pos,code) ONE ascending-c fma chain; z2 numpy pairwise
// 8-chain; d = fl(fl(z2-2zc)+c2); strict-< ascending-k; cross-subset
// lexicographic (d,k) min == np.argmin first-index tie-break.
__global__ __launch_bounds__(256, 1) void vq_main(const float* __restrict__ z,
                                                  const float* __restrict__ cb,
                                                  float* __restrict__ ws,
                                                  float* __restrict__ out) {
    __shared__ __align__(16) float zt[CDIM][P];     // 32 KB  zt[c][p]
    __shared__ __align__(16) float tile[TK * CDIM]; // 64 KB  swizzled [k][f^cg]
    __shared__ float z2s[P];                        // 256 B
    __shared__ float bdls[16][P];                   // 4 KB  per-cg best_d
    __shared__ int   bkls[16][P];                   // 4 KB  per-cg best_k
    __shared__ int   wkls[P];                       // 256 B winning code
    __shared__ float red[256];                      // 1 KB   (total ~105.5 KB)

    const int tid   = threadIdx.x;
    const int nbase = blockIdx.x * P;
    const int b     = nbase >> 12;          // 4096 positions per batch image
    const int hw0   = nbase & (HWSZ - 1);   // 64-aligned
    const float* zb = z + (size_t)b * CDIM * HWSZ + hw0;

    // ---- issue tile-0 global loads early (16 x dwordx4, L2-hot) ------------
    float4 st[16];
    {
        const float4* src = (const float4*)cb;
        #pragma unroll
        for (int i = 0; i < 16; ++i) st[i] = src[i * 256 + tid];
    }

    // ---- stage z strip: zt[c][p] = z[b][c][hw0+p] (coalesced) --------------
    #pragma unroll
    for (int i = 0; i < (CDIM * P / 4) / 256; ++i) {   // 8 iters
        const int linear = i * 256 + tid;              // 0..2047
        const int c  = linear >> 4;                    // 16 float4 per c-row
        const int p4 = (linear & 15) * 4;
        *(float4*)&zt[c][p4] = *(const float4*)(zb + (size_t)c * HWSZ + p4);
    }
    __syncthreads();

    // ---- z2 per position (wave 0) while all threads write tile 0 -----------
    if (tid < P) {
        const int p = tid;
        float r[8];
        #pragma unroll
        for (int j = 0; j < 8; ++j) {
            const float x = zt[j][p];
            r[j] = __fmul_rn(x, x);
        }
        #pragma unroll
        for (int i = 8; i < CDIM; i += 8) {
            #pragma unroll
            for (int j = 0; j < 8; ++j) {
                const float x = zt[i + j][p];
                r[j] = __fadd_rn(r[j], __fmul_rn(x, x));
            }
        }
        const float s01 = __fadd_rn(r[0], r[1]);
        const float s23 = __fadd_rn(r[2], r[3]);
        const float s45 = __fadd_rn(r[4], r[5]);
        const float s67 = __fadd_rn(r[6], r[7]);
        z2s[p] = __fadd_rn(__fadd_rn(s01, s23), __fadd_rn(s45, s67));
    }
    {   // swizzled write: float4 index f -> f ^ ((k>>3)&3)
        float4* t4 = (float4*)tile;
        #pragma unroll
        for (int i = 0; i < 16; ++i) {
            const int idx = i * 256 + tid;      // 0..4095
            const int k = idx >> 5;             // row (32 float4 per row)
            const int f = idx & 31;
            t4[(k << 5) | (f ^ ((k >> 3) & 3))] = st[i];
        }
    }
    __syncthreads();

    const int pg  = tid & 15;     // position group: p0..p0+3
    const int cg  = tid >> 4;     // code group 0..15: codes k0..k0+7 per tile
    const int p0  = pg * 4;
    const int k0  = cg * 8;
    const int scg = cg & 3;       // swizzle key: distinct across a wave
    const float* c2g = ws + WS_C2;

    float z2r[4];
    #pragma unroll
    for (int i = 0; i < 4; ++i) z2r[i] = z2s[p0 + i];

    float bestd[4] = {INFINITY, INFINITY, INFINITY, INFINITY};
    int   bestk[4] = {0, 0, 0, 0};

    const float4* t4 = (const float4*)tile;

    for (int t = 0; t < NTILES; ++t) {
        // issue next tile's global loads; latency hides under ~8200cy of FMA
        if (t + 1 < NTILES) {
            const float4* src = (const float4*)(cb + (size_t)(t + 1) * TK * CDIM);
            #pragma unroll
            for (int i = 0; i < 16; ++i) st[i] = src[i * 256 + tid];
        }

        float a[4][8];
        #pragma unroll
        for (int i = 0; i < 4; ++i)
            #pragma unroll
            for (int j = 0; j < 8; ++j) a[i][j] = 0.0f;

        // 32 independent fma chains, each ascending c (reference order).
        // 12 ds_read_b128 per 128 FMA; all conflict-free (z: 2-way inherent =
        // free; codes: swizzled to 4 distinct bank quads + 16-lane broadcast).
        #pragma unroll 2
        for (int c4 = 0; c4 < CDIM / 4; ++c4) {
            const int c = c4 * 4;
            const float4 zv0 = *(const float4*)&zt[c + 0][p0];
            const float4 zv1 = *(const float4*)&zt[c + 1][p0];
            const float4 zv2 = *(const float4*)&zt[c + 2][p0];
            const float4 zv3 = *(const float4*)&zt[c + 3][p0];
            const int col = c4 ^ scg;
            #pragma unroll
            for (int j = 0; j < 8; ++j) {
                const float4 cv = t4[((k0 + j) << 5) | col];
                a[0][j] = fmaf(zv0.x, cv.x, a[0][j]);
                a[0][j] = fmaf(zv1.x, cv.y, a[0][j]);
                a[0][j] = fmaf(zv2.x, cv.z, a[0][j]);
                a[0][j] = fmaf(zv3.x, cv.w, a[0][j]);
                a[1][j] = fmaf(zv0.y, cv.x, a[1][j]);
                a[1][j] = fmaf(zv1.y, cv.y, a[1][j]);
                a[1][j] = fmaf(zv2.y, cv.z, a[1][j]);
                a[1][j] = fmaf(zv3.y, cv.w, a[1][j]);
                a[2][j] = fmaf(zv0.z, cv.x, a[2][j]);
                a[2][j] = fmaf(zv1.z, cv.y, a[2][j]);
                a[2][j] = fmaf(zv2.z, cv.z, a[2][j]);
                a[2][j] = fmaf(zv3.z, cv.w, a[2][j]);
                a[3][j] = fmaf(zv0.w, cv.x, a[3][j]);
                a[3][j] = fmaf(zv1.w, cv.y, a[3][j]);
                a[3][j] = fmaf(zv2.w, cv.z, a[3][j]);
                a[3][j] = fmaf(zv3.w, cv.w, a[3][j]);
            }
        }

        // d = fl(fl(z2 - 2*zc) + c2); strict < with ascending k (t, then j)
        const int kb = t * TK + k0;
        #pragma unroll
        for (int j = 0; j < 8; ++j) {
            const float c2 = c2g[kb + j];
            #pragma unroll
            for (int i = 0; i < 4; ++i) {
                const float d = __fadd_rn(fmaf(-2.0f, a[i][j], z2r[i]), c2);
                if (d < bestd[i]) { bestd[i] = d; bestk[i] = kb + j; }
            }
        }

        __syncthreads();                 // all waves done reading tile t
        if (t + 1 < NTILES) {            // swizzled write of tile t+1
            float4* w4 = (float4*)tile;
            #pragma unroll
            for (int i = 0; i < 16; ++i) {
                const int idx = i * 256 + tid;
                const int k = idx >> 5;
                const int f = idx & 31;
                w4[(k << 5) | (f ^ ((k >> 3) & 3))] = st[i];
            }
            __syncthreads();
        }
    }

    #pragma unroll
    for (int i = 0; i < 4; ++i) {
        bdls[cg][p0 + i] = bestd[i];
        bkls[cg][p0 + i] = bestk[i];
    }
    __syncthreads();

    // ---- combine 16 disjoint code-subsets per position; lexicographic (d,k)
    unsigned int* ghist = (unsigned int*)ws + WS_HIST;
    if (tid < P) {
        const int p = tid;
        float bd = bdls[0][p];
        int   bk = bkls[0][p];
        #pragma unroll
        for (int g = 1; g < 16; ++g) {
            const float d = bdls[g][p];
            const int   k = bkls[g][p];
            if (d < bd || (d == bd && k < bk)) { bd = d; bk = k; }
        }
        wkls[p] = bk;
        out[IDX_OFF + (size_t)(nbase + p)] = (float)bk;
        atomicAdd(&ghist[bk], 1u);       // 64/block, 1024 bins: low contention
        red[tid] = bd;     // best_d == fl(||z-q||^2), loss has 2% slack
    } else {
        red[tid] = 0.0f;
    }
    __syncthreads();
    for (int s = 128; s > 0; s >>= 1) {
        if (tid < s) red[tid] += red[tid + s];
        __syncthreads();
    }
    if (tid == 0) atomicAdd(&ws[WS_LOSS], red[0]);

    // ---- quantized output: out[b][c][hw0+p] = cb[wk[p]][c] -----------------
    // stores coalesced (256B per c-row); cb gather L1/L2-hot.
    float* ob = out + (size_t)b * CDIM * HWSZ + hw0;
    #pragma unroll
    for (int i = 0; i < (CDIM * P) / 256; ++i) {   // 32 iters
        const int linear = i * 256 + tid;          // 0..8191
        const int c = linear >> 6;
        const int p = linear & 63;
        ob[(size_t)c * HWSZ + p] = cb[(size_t)wkls[p] * CDIM + c];
    }
}

// ---- pass 2: scalars --------------------------------------------------------
__global__ __launch_bounds__(1024) void vq_final(const float* __restrict__ ws,
                                                 float* __restrict__ out) {
    __shared__ float red[1024];
    const int t = threadIdx.x;
    const unsigned int* hist = (const unsigned int*)ws + WS_HIST;
    const float p = (float)hist[t] * INV_NPOS;
    red[t] = p * logf(p + 1e-10f);
    __syncthreads();
    for (int s = 512; s > 0; s >>= 1) {
        if (t < s) red[t] += red[t + s];
        __syncthreads();
    }
    if (t == 0) {
        out[LOSS_OFF] = 1.25f * (ws[WS_LOSS] * INV_TOTAL);   // cb + 0.25*commit
        out[PERP_OFF] = expf(-red[0]);
    }
}

extern "C" void kernel_launch(void* const* d_in, const int* in_sizes, int n_in,
                              void* d_out, int out_size, void* d_ws, size_t ws_size,
                              hipStream_t stream) {
    const float* z  = (const float*)d_in[0];
    const float* cb = (const float*)d_in[1];
    float* out = (float*)d_out;
    float* ws  = (float*)d_ws;

    vq_prep <<<KCODES / 256, 256, 0, stream>>>(cb, ws);
    vq_main <<<NPOS / P,     256, 0, stream>>>(z, cb, ws, out);
    vq_final<<<1,           1024, 0, stream>>>(ws, out);
}

// Round 7
// 358.422 us; speedup vs baseline: 1.2939x; 1.2939x over previous
//
#include <hip/hip_runtime.h>
#include <math.h>

namespace {
constexpr int CDIM   = 128;
constexpr int KCODES = 1024;
constexpr int HWSZ   = 4096;   // 64*64
constexpr int BATCH  = 16;
constexpr int NPOS   = BATCH * HWSZ;            // 65536
constexpr int P      = 64;                      // positions per block
constexpr int TK     = 128;                     // codes per LDS tile
constexpr int NTILES = KCODES / TK;             // 8
constexpr size_t QELEMS   = (size_t)BATCH * CDIM * HWSZ;   // 8388608
constexpr size_t IDX_OFF  = QELEMS;                        // float32 elements
constexpr size_t LOSS_OFF = IDX_OFF + (size_t)NPOS;        // 8454144
constexpr size_t PERP_OFF = LOSS_OFF + 1;
// d_ws float-element offsets
constexpr int WS_C2   = 0;      // [0,1024)   float ||c_k||^2 (numpy-bit-exact)
constexpr int WS_HIST = 1024;   // [1024,2048) uint  usage counts
constexpr int WS_LOSS = 2048;   // [2048]     float sum ||z-q||^2
constexpr float INV_TOTAL = 1.0f / (float)QELEMS;
constexpr float INV_NPOS  = 1.0f / (float)NPOS;
}

// Bit-exact replica of numpy pairwise_sum for n=128 contiguous float32 applied
// to elementwise squares: 8 accumulator chains (stride 8), sequential within a
// chain, combined ((r0+r1)+(r2+r3))+((r4+r5)+(r6+r7)). __f*_rn forbids fma
// contraction (numpy multiplies into a temp, then adds — never fused).
__device__ __forceinline__ float np_sumsq_128(const float* v) {
    float r[8];
    #pragma unroll
    for (int j = 0; j < 8; ++j) r[j] = __fmul_rn(v[j], v[j]);
    #pragma unroll
    for (int i = 8; i < 128; i += 8) {
        #pragma unroll
        for (int j = 0; j < 8; ++j)
            r[j] = __fadd_rn(r[j], __fmul_rn(v[i + j], v[i + j]));
    }
    const float s01 = __fadd_rn(r[0], r[1]);
    const float s23 = __fadd_rn(r[2], r[3]);
    const float s45 = __fadd_rn(r[4], r[5]);
    const float s67 = __fadd_rn(r[6], r[7]);
    return __fadd_rn(__fadd_rn(s01, s23), __fadd_rn(s45, s67));
}

// ---- pass 0: codebook norms (numpy-bit-exact) + zero accumulators ----------
__global__ __launch_bounds__(256) void vq_prep(const float* __restrict__ cb,
                                               float* __restrict__ ws) {
    const int k = blockIdx.x * 256 + threadIdx.x;   // 0..1023
    const float* row = cb + (size_t)k * CDIM;
    float rr[CDIM];
    #pragma unroll
    for (int c = 0; c < CDIM; ++c) rr[c] = row[c];
    ws[WS_C2 + k] = np_sumsq_128(rr);
    ((unsigned int*)ws)[WS_HIST + k] = 0u;
    if (k == 0) ws[WS_LOSS] = 0.0f;
}

// ---- pass 1: register-blocked GEMM-style argmin -----------------------------
// Round 6: R5 (64-acc tile, P=128) killed the container twice — prime suspect
// is compile-stage blowup from the 512-FMA fully-unrolled region. De-risk:
// return to R4's structure (P=64, TK=128, thread tile 4 pos x 8 codes = 32
// acc), which compiled and ran, and apply ONLY the spill fix: no register-
// resident prefetch (R4's st[16] caused WRITE_SIZE 34->250MB scratch);
// tile t+1 is staged SYNCHRONOUSLY (load -> ds_write, transient regs only)
// between barriers. DS budget (R3 calibration ~4.8cy/DS-inst): 12 DS per 128
// FMA per wave -> per CU 4x12x4.8 = 230cy DS < 256cy VALU -> VALU-bound.
// Code-tile XOR swizzle (R4, measured conflicts->0): float4 col f -> f^((k>>3)&3)
// on write and read; 4 cgroups/wave hit 4 distinct bank quads + 16-lane bcast;
// z reads 2-way (free). Bit-exactness: per (pos,code) ONE ascending-c fma
// chain (c,c+1,c+2,c+3 in chunk, chunks ascend); z2 numpy pairwise 8-chain;
// d = fl(fl(z2-2zc)+c2); strict-< ascending-k; cross-subset lexicographic
// (d,k) min == np.argmin first-index tie-break.
__global__ __launch_bounds__(256, 1) void vq_main(const float* __restrict__ z,
                                                  const float* __restrict__ cb,
                                                  float* __restrict__ ws,
                                                  float* __restrict__ out) {
    __shared__ __align__(16) float zt[CDIM][P];     // 32 KB  zt[c][p]
    __shared__ __align__(16) float tile[TK * CDIM]; // 64 KB  swizzled [k][f^..]
    __shared__ float z2s[P];                        // 256 B
    __shared__ float bdls[16][P];                   // 4 KB  per-cg best_d
    __shared__ int   bkls[16][P];                   // 4 KB  per-cg best_k
    __shared__ int   wkls[P];                       // 256 B winning code
    __shared__ float red[256];                      // 1 KB   (total ~105.5 KB)

    const int tid   = threadIdx.x;
    const int nbase = blockIdx.x * P;
    const int b     = nbase >> 12;          // 4096 positions per batch image
    const int hw0   = nbase & (HWSZ - 1);   // 64-aligned
    const float* zb = z + (size_t)b * CDIM * HWSZ + hw0;

    // ---- stage z strip: zt[c][p] = z[b][c][hw0+p] (coalesced) --------------
    #pragma unroll
    for (int i = 0; i < (CDIM * P / 4) / 256; ++i) {   // 8 iters
        const int linear = i * 256 + tid;              // 0..2047
        const int c  = linear >> 4;                    // 16 float4 per c-row
        const int p4 = (linear & 15) * 4;
        *(float4*)&zt[c][p4] = *(const float4*)(zb + (size_t)c * HWSZ + p4);
    }
    // ---- stage tile 0 (swizzled write, transient regs only) ----------------
    {
        const float4* src = (const float4*)cb;
        float4* w4 = (float4*)tile;
        #pragma unroll
        for (int i = 0; i < 16; ++i) {
            const int idx = i * 256 + tid;      // 0..4095
            const int k = idx >> 5;             // 32 float4 per row
            const int f = idx & 31;
            w4[(k << 5) | (f ^ ((k >> 3) & 3))] = src[idx];
        }
    }
    __syncthreads();

    // ---- z2 per position: numpy pairwise 8-chain, streamed from LDS --------
    if (tid < P) {
        const int p = tid;
        float r[8];
        #pragma unroll
        for (int j = 0; j < 8; ++j) {
            const float x = zt[j][p];
            r[j] = __fmul_rn(x, x);
        }
        #pragma unroll
        for (int i = 8; i < CDIM; i += 8) {
            #pragma unroll
            for (int j = 0; j < 8; ++j) {
                const float x = zt[i + j][p];
                r[j] = __fadd_rn(r[j], __fmul_rn(x, x));
            }
        }
        const float s01 = __fadd_rn(r[0], r[1]);
        const float s23 = __fadd_rn(r[2], r[3]);
        const float s45 = __fadd_rn(r[4], r[5]);
        const float s67 = __fadd_rn(r[6], r[7]);
        z2s[p] = __fadd_rn(__fadd_rn(s01, s23), __fadd_rn(s45, s67));
    }
    __syncthreads();

    const int pg  = tid & 15;     // position group: p0..p0+3
    const int cg  = tid >> 4;     // code group 0..15: codes k0..k0+7 per tile
    const int p0  = pg * 4;
    const int k0  = cg * 8;
    const int scg = cg & 3;       // swizzle key: distinct across each wave
    const float* c2g = ws + WS_C2;

    float z2r[4];
    #pragma unroll
    for (int i = 0; i < 4; ++i) z2r[i] = z2s[p0 + i];

    float bestd[4] = {INFINITY, INFINITY, INFINITY, INFINITY};
    int   bestk[4] = {0, 0, 0, 0};

    const float4* t4 = (const float4*)tile;

    for (int t = 0; t < NTILES; ++t) {
        float a[4][8];
        #pragma unroll
        for (int i = 0; i < 4; ++i)
            #pragma unroll
            for (int j = 0; j < 8; ++j) a[i][j] = 0.0f;

        // 32 independent fma chains, each ascending c (reference order).
        // 12 ds_read_b128 per 128 FMAs per wave; z 2-way (free), codes
        // conflict-free via swizzle (R4: SQ_LDS_BANK_CONFLICT -> 0).
        #pragma unroll 2
        for (int c4 = 0; c4 < CDIM / 4; ++c4) {
            const int c = c4 * 4;
            const float4 zv0 = *(const float4*)&zt[c + 0][p0];
            const float4 zv1 = *(const float4*)&zt[c + 1][p0];
            const float4 zv2 = *(const float4*)&zt[c + 2][p0];
            const float4 zv3 = *(const float4*)&zt[c + 3][p0];
            const int col = c4 ^ scg;
            #pragma unroll
            for (int j = 0; j < 8; ++j) {
                const float4 cv = t4[((k0 + j) << 5) | col];
                a[0][j] = fmaf(zv0.x, cv.x, a[0][j]);
                a[0][j] = fmaf(zv1.x, cv.y, a[0][j]);
                a[0][j] = fmaf(zv2.x, cv.z, a[0][j]);
                a[0][j] = fmaf(zv3.x, cv.w, a[0][j]);
                a[1][j] = fmaf(zv0.y, cv.x, a[1][j]);
                a[1][j] = fmaf(zv1.y, cv.y, a[1][j]);
                a[1][j] = fmaf(zv2.y, cv.z, a[1][j]);
                a[1][j] = fmaf(zv3.y, cv.w, a[1][j]);
                a[2][j] = fmaf(zv0.z, cv.x, a[2][j]);
                a[2][j] = fmaf(zv1.z, cv.y, a[2][j]);
                a[2][j] = fmaf(zv2.z, cv.z, a[2][j]);
                a[2][j] = fmaf(zv3.z, cv.w, a[2][j]);
                a[3][j] = fmaf(zv0.w, cv.x, a[3][j]);
                a[3][j] = fmaf(zv1.w, cv.y, a[3][j]);
                a[3][j] = fmaf(zv2.w, cv.z, a[3][j]);
                a[3][j] = fmaf(zv3.w, cv.w, a[3][j]);
            }
        }

        // d = fl(fl(z2 - 2*zc) + c2); strict < with ascending k (t, then j)
        const int kb = t * TK + k0;
        #pragma unroll
        for (int j = 0; j < 8; ++j) {
            const float c2 = c2g[kb + j];
            #pragma unroll
            for (int i = 0; i < 4; ++i) {
                const float d = __fadd_rn(fmaf(-2.0f, a[i][j], z2r[i]), c2);
                if (d < bestd[i]) { bestd[i] = d; bestk[i] = kb + j; }
            }
        }

        // ---- synchronous staging of tile t+1 (transient regs only) ---------
        if (t + 1 < NTILES) {
            __syncthreads();             // all waves done reading tile t
            const float4* src = (const float4*)(cb + (size_t)(t + 1) * TK * CDIM);
            float4* w4 = (float4*)tile;
            #pragma unroll
            for (int i = 0; i < 16; ++i) {
                const int idx = i * 256 + tid;
                const int k = idx >> 5;
                const int f = idx & 31;
                w4[(k << 5) | (f ^ ((k >> 3) & 3))] = src[idx];
            }
            __syncthreads();
        }
    }

    #pragma unroll
    for (int i = 0; i < 4; ++i) {
        bdls[cg][p0 + i] = bestd[i];
        bkls[cg][p0 + i] = bestk[i];
    }
    __syncthreads();

    // ---- combine 16 disjoint code-subsets per position; lexicographic (d,k)
    unsigned int* ghist = (unsigned int*)ws + WS_HIST;
    if (tid < P) {
        const int p = tid;
        float bd = bdls[0][p];
        int   bk = bkls[0][p];
        #pragma unroll
        for (int g = 1; g < 16; ++g) {
            const float d = bdls[g][p];
            const int   k = bkls[g][p];
            if (d < bd || (d == bd && k < bk)) { bd = d; bk = k; }
        }
        wkls[p] = bk;
        out[IDX_OFF + (size_t)(nbase + p)] = (float)bk;
        atomicAdd(&ghist[bk], 1u);       // 64/block, 1024 bins: low contention
        red[tid] = bd;     // best_d == fl(||z-q||^2), loss has 2% slack
    } else {
        red[tid] = 0.0f;
    }
    __syncthreads();
    for (int s = 128; s > 0; s >>= 1) {
        if (tid < s) red[tid] += red[tid + s];
        __syncthreads();
    }
    if (tid == 0) atomicAdd(&ws[WS_LOSS], red[0]);

    // ---- quantized output: out[b][c][hw0+p] = cb[wk[p]][c] -----------------
    // stores coalesced (256B per c-row); cb gather L1/L2-hot.
    float* ob = out + (size_t)b * CDIM * HWSZ + hw0;
    #pragma unroll
    for (int i = 0; i < (CDIM * P) / 256; ++i) {   // 32 iters
        const int linear = i * 256 + tid;          // 0..8191
        const int c = linear >> 6;
        const int p = linear & 63;
        ob[(size_t)c * HWSZ + p] = cb[(size_t)wkls[p] * CDIM + c];
    }
}

// ---- pass 2: scalars --------------------------------------------------------
__global__ __launch_bounds__(1024) void vq_final(const float* __restrict__ ws,
                                                 float* __restrict__ out) {
    __shared__ float red[1024];
    const int t = threadIdx.x;
    const unsigned int* hist = (const unsigned int*)ws + WS_HIST;
    const float p = (float)hist[t] * INV_NPOS;
    red[t] = p * logf(p + 1e-10f);
    __syncthreads();
    for (int s = 512; s > 0; s >>= 1) {
        if (t < s) red[t] += red[t + s];
        __syncthreads();
    }
    if (t == 0) {
        out[LOSS_OFF] = 1.25f * (ws[WS_LOSS] * INV_TOTAL);   // cb + 0.25*commit
        out[PERP_OFF] = expf(-red[0]);
    }
}

extern "C" void kernel_launch(void* const* d_in, const int* in_sizes, int n_in,
                              void* d_out, int out_size, void* d_ws, size_t ws_size,
                              hipStream_t stream) {
    const float* z  = (const float*)d_in[0];
    const float* cb = (const float*)d_in[1];
    float* out = (float*)d_out;
    float* ws  = (float*)d_ws;

    vq_prep <<<KCODES / 256, 256, 0, stream>>>(cb, ws);
    vq_main <<<NPOS / P,     256, 0, stream>>>(z, cb, ws, out);
    vq_final<<<1,           1024, 0, stream>>>(ws, out);
}

// Round 8
// 357.945 us; speedup vs baseline: 1.2956x; 1.0013x over previous
//
#include <hip/hip_runtime.h>
#include <math.h>

namespace {
constexpr int CDIM   = 128;
constexpr int KCODES = 1024;
constexpr int HWSZ   = 4096;   // 64*64
constexpr int BATCH  = 16;
constexpr int NPOS   = BATCH * HWSZ;            // 65536
constexpr int P      = 64;                      // positions per block
constexpr int TK     = 128;                     // codes per LDS tile
constexpr int NTILES = KCODES / TK;             // 8
constexpr size_t QELEMS   = (size_t)BATCH * CDIM * HWSZ;   // 8388608
constexpr size_t IDX_OFF  = QELEMS;                        // float32 elements
constexpr size_t LOSS_OFF = IDX_OFF + (size_t)NPOS;        // 8454144
constexpr size_t PERP_OFF = LOSS_OFF + 1;
// d_ws float-element offsets
constexpr int WS_C2   = 0;      // [0,1024)   float ||c_k||^2 (numpy-bit-exact)
constexpr int WS_HIST = 1024;   // [1024,2048) uint  usage counts
constexpr int WS_LOSS = 2048;   // [2048]     float sum ||z-q||^2
constexpr float INV_TOTAL = 1.0f / (float)QELEMS;
constexpr float INV_NPOS  = 1.0f / (float)NPOS;
}

// Bit-exact replica of numpy pairwise_sum for n=128 contiguous float32 applied
// to elementwise squares: 8 accumulator chains (stride 8), sequential within a
// chain, combined ((r0+r1)+(r2+r3))+((r4+r5)+(r6+r7)). __f*_rn forbids fma
// contraction (numpy multiplies into a temp, then adds — never fused).
__device__ __forceinline__ float np_sumsq_128(const float* v) {
    float r[8];
    #pragma unroll
    for (int j = 0; j < 8; ++j) r[j] = __fmul_rn(v[j], v[j]);
    #pragma unroll
    for (int i = 8; i < 128; i += 8) {
        #pragma unroll
        for (int j = 0; j < 8; ++j)
            r[j] = __fadd_rn(r[j], __fmul_rn(v[i + j], v[i + j]));
    }
    const float s01 = __fadd_rn(r[0], r[1]);
    const float s23 = __fadd_rn(r[2], r[3]);
    const float s45 = __fadd_rn(r[4], r[5]);
    const float s67 = __fadd_rn(r[6], r[7]);
    return __fadd_rn(__fadd_rn(s01, s23), __fadd_rn(s45, s67));
}

// ---- pass 0: codebook norms (numpy-bit-exact) + zero accumulators ----------
__global__ __launch_bounds__(256) void vq_prep(const float* __restrict__ cb,
                                               float* __restrict__ ws) {
    const int k = blockIdx.x * 256 + threadIdx.x;   // 0..1023
    const float* row = cb + (size_t)k * CDIM;
    float rr[CDIM];
    #pragma unroll
    for (int c = 0; c < CDIM; ++c) rr[c] = row[c];
    ws[WS_C2 + k] = np_sumsq_128(rr);
    ((unsigned int*)ws)[WS_HIST + k] = 0u;
    if (k == 0) ws[WS_LOSS] = 0.0f;
}

// ---- pass 1: register-blocked GEMM-style argmin -----------------------------
// Round 8: R2/R3/R7 all pinned at VALUBusy ~50/55/49% across DIFFERENT DS
// ratios and occupancies -> the invariant is the FMA emission idiom: each
// accumulator's 4 per-chunk FMAs were emitted back-to-back, and v_fma_f32 has
// ~4cy dependent latency vs 2cy issue -> source-ordered dependent chain = 50%
// VALU ceiling, un-fillable at 1 wave/SIMD. Fix (single variable vs R7):
// emit FMAs CHANNEL-MAJOR across the 32 independent accumulators (all 32 at
// channel c, then all at c+1, ...). Each acc still accumulates in ascending-c
// order -> per-chain rounding sequence bit-identical; only inter-chain
// interleave changes. Dependency distance 1 -> 32 insts.
// Everything else identical to R7 (compiled+ran: 320us, conflicts 0, no
// spill): P=64, TK=128, 4pos x 8codes, XOR-swizzled code tile, synchronous
// staging with transient regs between barriers.
// Bit-exactness: per (pos,code) ONE ascending-c fma chain; z2 numpy pairwise
// 8-chain; d = fl(fl(z2-2zc)+c2); strict-< ascending-k; cross-subset
// lexicographic (d,k) min == np.argmin first-index tie-break.
__global__ __launch_bounds__(256, 1) void vq_main(const float* __restrict__ z,
                                                  const float* __restrict__ cb,
                                                  float* __restrict__ ws,
                                                  float* __restrict__ out) {
    __shared__ __align__(16) float zt[CDIM][P];     // 32 KB  zt[c][p]
    __shared__ __align__(16) float tile[TK * CDIM]; // 64 KB  swizzled [k][f^..]
    __shared__ float z2s[P];                        // 256 B
    __shared__ float bdls[16][P];                   // 4 KB  per-cg best_d
    __shared__ int   bkls[16][P];                   // 4 KB  per-cg best_k
    __shared__ int   wkls[P];                       // 256 B winning code
    __shared__ float red[256];                      // 1 KB   (total ~105.5 KB)

    const int tid   = threadIdx.x;
    const int nbase = blockIdx.x * P;
    const int b     = nbase >> 12;          // 4096 positions per batch image
    const int hw0   = nbase & (HWSZ - 1);   // 64-aligned
    const float* zb = z + (size_t)b * CDIM * HWSZ + hw0;

    // ---- stage z strip: zt[c][p] = z[b][c][hw0+p] (coalesced) --------------
    #pragma unroll
    for (int i = 0; i < (CDIM * P / 4) / 256; ++i) {   // 8 iters
        const int linear = i * 256 + tid;              // 0..2047
        const int c  = linear >> 4;                    // 16 float4 per c-row
        const int p4 = (linear & 15) * 4;
        *(float4*)&zt[c][p4] = *(const float4*)(zb + (size_t)c * HWSZ + p4);
    }
    // ---- stage tile 0 (swizzled write, transient regs only) ----------------
    {
        const float4* src = (const float4*)cb;
        float4* w4 = (float4*)tile;
        #pragma unroll
        for (int i = 0; i < 16; ++i) {
            const int idx = i * 256 + tid;      // 0..4095
            const int k = idx >> 5;             // 32 float4 per row
            const int f = idx & 31;
            w4[(k << 5) | (f ^ ((k >> 3) & 3))] = src[idx];
        }
    }
    __syncthreads();

    // ---- z2 per position: numpy pairwise 8-chain, streamed from LDS --------
    if (tid < P) {
        const int p = tid;
        float r[8];
        #pragma unroll
        for (int j = 0; j < 8; ++j) {
            const float x = zt[j][p];
            r[j] = __fmul_rn(x, x);
        }
        #pragma unroll
        for (int i = 8; i < CDIM; i += 8) {
            #pragma unroll
            for (int j = 0; j < 8; ++j) {
                const float x = zt[i + j][p];
                r[j] = __fadd_rn(r[j], __fmul_rn(x, x));
            }
        }
        const float s01 = __fadd_rn(r[0], r[1]);
        const float s23 = __fadd_rn(r[2], r[3]);
        const float s45 = __fadd_rn(r[4], r[5]);
        const float s67 = __fadd_rn(r[6], r[7]);
        z2s[p] = __fadd_rn(__fadd_rn(s01, s23), __fadd_rn(s45, s67));
    }
    __syncthreads();

    const int pg  = tid & 15;     // position group: p0..p0+3
    const int cg  = tid >> 4;     // code group 0..15: codes k0..k0+7 per tile
    const int p0  = pg * 4;
    const int k0  = cg * 8;
    const int scg = cg & 3;       // swizzle key: distinct across each wave
    const float* c2g = ws + WS_C2;

    float z2r[4];
    #pragma unroll
    for (int i = 0; i < 4; ++i) z2r[i] = z2s[p0 + i];

    float bestd[4] = {INFINITY, INFINITY, INFINITY, INFINITY};
    int   bestk[4] = {0, 0, 0, 0};

    const float4* t4 = (const float4*)tile;

    for (int t = 0; t < NTILES; ++t) {
        float a[4][8];
        #pragma unroll
        for (int i = 0; i < 4; ++i)
            #pragma unroll
            for (int j = 0; j < 8; ++j) a[i][j] = 0.0f;

        // 32 independent fma chains, each ascending c (reference order).
        // Channel-major emission: 32 independent FMAs back-to-back per
        // channel step -> no dependent-latency bubbles.
        #pragma unroll 2
        for (int c4 = 0; c4 < CDIM / 4; ++c4) {
            const int c = c4 * 4;
            const float4 zv0 = *(const float4*)&zt[c + 0][p0];
            const float4 zv1 = *(const float4*)&zt[c + 1][p0];
            const float4 zv2 = *(const float4*)&zt[c + 2][p0];
            const float4 zv3 = *(const float4*)&zt[c + 3][p0];
            const int col = c4 ^ scg;
            float4 cv[8];
            #pragma unroll
            for (int j = 0; j < 8; ++j) cv[j] = t4[((k0 + j) << 5) | col];
            // channel c+0
            #pragma unroll
            for (int j = 0; j < 8; ++j) {
                a[0][j] = fmaf(zv0.x, cv[j].x, a[0][j]);
                a[1][j] = fmaf(zv0.y, cv[j].x, a[1][j]);
                a[2][j] = fmaf(zv0.z, cv[j].x, a[2][j]);
                a[3][j] = fmaf(zv0.w, cv[j].x, a[3][j]);
            }
            // channel c+1
            #pragma unroll
            for (int j = 0; j < 8; ++j) {
                a[0][j] = fmaf(zv1.x, cv[j].y, a[0][j]);
                a[1][j] = fmaf(zv1.y, cv[j].y, a[1][j]);
                a[2][j] = fmaf(zv1.z, cv[j].y, a[2][j]);
                a[3][j] = fmaf(zv1.w, cv[j].y, a[3][j]);
            }
            // channel c+2
            #pragma unroll
            for (int j = 0; j < 8; ++j) {
                a[0][j] = fmaf(zv2.x, cv[j].z, a[0][j]);
                a[1][j] = fmaf(zv2.y, cv[j].z, a[1][j]);
                a[2][j] = fmaf(zv2.z, cv[j].z, a[2][j]);
                a[3][j] = fmaf(zv2.w, cv[j].z, a[3][j]);
            }
            // channel c+3
            #pragma unroll
            for (int j = 0; j < 8; ++j) {
                a[0][j] = fmaf(zv3.x, cv[j].w, a[0][j]);
                a[1][j] = fmaf(zv3.y, cv[j].w, a[1][j]);
                a[2][j] = fmaf(zv3.z, cv[j].w, a[2][j]);
                a[3][j] = fmaf(zv3.w, cv[j].w, a[3][j]);
            }
        }

        // d = fl(fl(z2 - 2*zc) + c2); strict < with ascending k (t, then j)
        const int kb = t * TK + k0;
        #pragma unroll
        for (int j = 0; j < 8; ++j) {
            const float c2 = c2g[kb + j];
            #pragma unroll
            for (int i = 0; i < 4; ++i) {
                const float d = __fadd_rn(fmaf(-2.0f, a[i][j], z2r[i]), c2);
                if (d < bestd[i]) { bestd[i] = d; bestk[i] = kb + j; }
            }
        }

        // ---- synchronous staging of tile t+1 (transient regs only) ---------
        if (t + 1 < NTILES) {
            __syncthreads();             // all waves done reading tile t
            const float4* src = (const float4*)(cb + (size_t)(t + 1) * TK * CDIM);
            float4* w4 = (float4*)tile;
            #pragma unroll
            for (int i = 0; i < 16; ++i) {
                const int idx = i * 256 + tid;
                const int k = idx >> 5;
                const int f = idx & 31;
                w4[(k << 5) | (f ^ ((k >> 3) & 3))] = src[idx];
            }
            __syncthreads();
        }
    }

    #pragma unroll
    for (int i = 0; i < 4; ++i) {
        bdls[cg][p0 + i] = bestd[i];
        bkls[cg][p0 + i] = bestk[i];
    }
    __syncthreads();

    // ---- combine 16 disjoint code-subsets per position; lexicographic (d,k)
    unsigned int* ghist = (unsigned int*)ws + WS_HIST;
    if (tid < P) {
        const int p = tid;
        float bd = bdls[0][p];
        int   bk = bkls[0][p];
        #pragma unroll
        for (int g = 1; g < 16; ++g) {
            const float d = bdls[g][p];
            const int   k = bkls[g][p];
            if (d < bd || (d == bd && k < bk)) { bd = d; bk = k; }
        }
        wkls[p] = bk;
        out[IDX_OFF + (size_t)(nbase + p)] = (float)bk;
        atomicAdd(&ghist[bk], 1u);       // 64/block, 1024 bins: low contention
        red[tid] = bd;     // best_d == fl(||z-q||^2), loss has 2% slack
    } else {
        red[tid] = 0.0f;
    }
    __syncthreads();
    for (int s = 128; s > 0; s >>= 1) {
        if (tid < s) red[tid] += red[tid + s];
        __syncthreads();
    }
    if (tid == 0) atomicAdd(&ws[WS_LOSS], red[0]);

    // ---- quantized output: out[b][c][hw0+p] = cb[wk[p]][c] -----------------
    // stores coalesced (256B per c-row); cb gather L1/L2-hot.
    float* ob = out + (size_t)b * CDIM * HWSZ + hw0;
    #pragma unroll
    for (int i = 0; i < (CDIM * P) / 256; ++i) {   // 32 iters
        const int linear = i * 256 + tid;          // 0..8191
        const int c = linear >> 6;
        const int p = linear & 63;
        ob[(size_t)c * HWSZ + p] = cb[(size_t)wkls[p] * CDIM + c];
    }
}

// ---- pass 2: scalars --------------------------------------------------------
__global__ __launch_bounds__(1024) void vq_final(const float* __restrict__ ws,
                                                 float* __restrict__ out) {
    __shared__ float red[1024];
    const int t = threadIdx.x;
    const unsigned int* hist = (const unsigned int*)ws + WS_HIST;
    const float p = (float)hist[t] * INV_NPOS;
    red[t] = p * logf(p + 1e-10f);
    __syncthreads();
    for (int s = 512; s > 0; s >>= 1) {
        if (t < s) red[t] += red[t + s];
        __syncthreads();
    }
    if (t == 0) {
        out[LOSS_OFF] = 1.25f * (ws[WS_LOSS] * INV_TOTAL);   // cb + 0.25*commit
        out[PERP_OFF] = expf(-red[0]);
    }
}

extern "C" void kernel_launch(void* const* d_in, const int* in_sizes, int n_in,
                              void* d_out, int out_size, void* d_ws, size_t ws_size,
                              hipStream_t stream) {
    const float* z  = (const float*)d_in[0];
    const float* cb = (const float*)d_in[1];
    float* out = (float*)d_out;
    float* ws  = (float*)d_ws;

    vq_prep <<<KCODES / 256, 256, 0, stream>>>(cb, ws);
    vq_main <<<NPOS / P,     256, 0, stream>>>(z, cb, ws, out);
    vq_final<<<1,           1024, 0, stream>>>(ws, out);
}

// Round 9
// 313.332 us; speedup vs baseline: 1.4801x; 1.1424x over previous
//
#include <hip/hip_runtime.h>
#include <math.h>

namespace {
constexpr int CDIM   = 128;
constexpr int KCODES = 1024;
constexpr int HWSZ   = 4096;   // 64*64
constexpr int BATCH  = 16;
constexpr int NPOS   = BATCH * HWSZ;            // 65536
constexpr int P      = 128;                     // positions per block
constexpr int TK     = 128;                     // codes per LDS tile
constexpr int NTILES = KCODES / TK;             // 8
constexpr int THREADS = 512;                    // 8 waves -> 2 waves/SIMD
constexpr size_t QELEMS   = (size_t)BATCH * CDIM * HWSZ;   // 8388608
constexpr size_t IDX_OFF  = QELEMS;                        // float32 elements
constexpr size_t LOSS_OFF = IDX_OFF + (size_t)NPOS;        // 8454144
constexpr size_t PERP_OFF = LOSS_OFF + 1;
// d_ws float-element offsets
constexpr int WS_C2   = 0;      // [0,1024)   float ||c_k||^2 (numpy-bit-exact)
constexpr int WS_HIST = 1024;   // [1024,2048) uint  usage counts
constexpr int WS_LOSS = 2048;   // [2048]     float sum ||z-q||^2
constexpr float INV_TOTAL = 1.0f / (float)QELEMS;
constexpr float INV_NPOS  = 1.0f / (float)NPOS;
}

// Bit-exact replica of numpy pairwise_sum for n=128 contiguous float32 applied
// to elementwise squares: 8 accumulator chains (stride 8), sequential within a
// chain, combined ((r0+r1)+(r2+r3))+((r4+r5)+(r6+r7)). __f*_rn forbids fma
// contraction (numpy multiplies into a temp, then adds — never fused).
__device__ __forceinline__ float np_sumsq_128(const float* v) {
    float r[8];
    #pragma unroll
    for (int j = 0; j < 8; ++j) r[j] = __fmul_rn(v[j], v[j]);
    #pragma unroll
    for (int i = 8; i < 128; i += 8) {
        #pragma unroll
        for (int j = 0; j < 8; ++j)
            r[j] = __fadd_rn(r[j], __fmul_rn(v[i + j], v[i + j]));
    }
    const float s01 = __fadd_rn(r[0], r[1]);
    const float s23 = __fadd_rn(r[2], r[3]);
    const float s45 = __fadd_rn(r[4], r[5]);
    const float s67 = __fadd_rn(r[6], r[7]);
    return __fadd_rn(__fadd_rn(s01, s23), __fadd_rn(s45, s67));
}

// ---- pass 0: codebook norms (numpy-bit-exact) + zero accumulators ----------
__global__ __launch_bounds__(256) void vq_prep(const float* __restrict__ cb,
                                               float* __restrict__ ws) {
    const int k = blockIdx.x * 256 + threadIdx.x;   // 0..1023
    const float* row = cb + (size_t)k * CDIM;
    float rr[CDIM];
    #pragma unroll
    for (int c = 0; c < CDIM; ++c) rr[c] = row[c];
    ws[WS_C2 + k] = np_sumsq_128(rr);
    ((unsigned int*)ws)[WS_HIST + k] = 0u;
    if (k == 0) ws[WS_LOSS] = 0.0f;
}

// ---- pass 1: register-blocked GEMM-style argmin -----------------------------
// Round 9. Evidence: VALUBusy pinned 49-55% in EVERY config; R8 proved source
// FMA order is irrelevant (identical codegen). Per-tile math: chunk takes
// ~520cy vs 256cy FMA -> ~260cy exposed LDS latency/pipe per chunk that one
// wave/SIMD cannot hide. R3 (2 waves/SIMD) had 2x worse DS ratio; R7 (best DS
// ratio 12 DS/128 FMA) had 1 wave/SIMD. This round combines both proven
// half-fixes: SAME per-thread tile as R7 (4 pos x 8 codes, identical inner
// code = known-good compile), but 512 threads (8 waves = 2 waves/SIMD),
// P=128, TK=128. LDS 147KB -> 1 block/CU. Staging amortizes 2x; grid 512 = 2
// generations; code reads now <=2 distinct addrs/instr.
// Code-tile XOR swizzle (proven conflicts->0): float4 col f -> f^((k>>3)&3) on
// write, col = c4^(cg&3) on read. Staging synchronous, transient regs only
// (R4 spill lesson). Bit-exactness: per (pos,code) ONE ascending-c fma chain
// (c,c+1,c+2,c+3 in chunk, chunks ascend); z2 numpy pairwise 8-chain;
// d = fl(fl(z2-2zc)+c2); strict-< ascending-k; cross-subset lexicographic
// (d,k) min == np.argmin first-index tie-break.
__global__ __launch_bounds__(512, 1) void vq_main(const float* __restrict__ z,
                                                  const float* __restrict__ cb,
                                                  float* __restrict__ ws,
                                                  float* __restrict__ out) {
    __shared__ __align__(16) float zt[CDIM][P];     // 64 KB  zt[c][p]
    __shared__ __align__(16) float tile[TK * CDIM]; // 64 KB  swizzled [k][f^..]
    __shared__ float z2s[P];                        // 512 B
    __shared__ float bdls[16][P];                   // 8 KB  per-cg best_d
    __shared__ int   bkls[16][P];                   // 8 KB  per-cg best_k
    __shared__ int   wkls[P];                       // 512 B winning code
    __shared__ float red[THREADS];                  // 2 KB   (total ~147 KB)

    const int tid   = threadIdx.x;
    const int nbase = blockIdx.x * P;
    const int b     = nbase >> 12;          // 4096 positions per batch image
    const int hw0   = nbase & (HWSZ - 1);   // 128-aligned
    const float* zb = z + (size_t)b * CDIM * HWSZ + hw0;

    // ---- stage z strip: zt[c][p] = z[b][c][hw0+p] (coalesced) --------------
    #pragma unroll
    for (int i = 0; i < (CDIM * P / 4) / THREADS; ++i) {   // 8 iters
        const int linear = i * THREADS + tid;              // 0..4095
        const int c  = linear >> 5;                        // 32 float4 per row
        const int p4 = (linear & 31) * 4;
        *(float4*)&zt[c][p4] = *(const float4*)(zb + (size_t)c * HWSZ + p4);
    }
    // ---- stage tile 0 (swizzled write, transient regs only) ----------------
    {
        const float4* src = (const float4*)cb;
        float4* w4 = (float4*)tile;
        #pragma unroll
        for (int i = 0; i < (TK * CDIM / 4) / THREADS; ++i) {   // 8 iters
            const int idx = i * THREADS + tid;  // 0..4095
            const int k = idx >> 5;             // 32 float4 per row
            const int f = idx & 31;
            w4[(k << 5) | (f ^ ((k >> 3) & 3))] = src[idx];
        }
    }
    __syncthreads();

    // ---- z2 per position: numpy pairwise 8-chain, streamed from LDS --------
    if (tid < P) {
        const int p = tid;
        float r[8];
        #pragma unroll
        for (int j = 0; j < 8; ++j) {
            const float x = zt[j][p];
            r[j] = __fmul_rn(x, x);
        }
        #pragma unroll
        for (int i = 8; i < CDIM; i += 8) {
            #pragma unroll
            for (int j = 0; j < 8; ++j) {
                const float x = zt[i + j][p];
                r[j] = __fadd_rn(r[j], __fmul_rn(x, x));
            }
        }
        const float s01 = __fadd_rn(r[0], r[1]);
        const float s23 = __fadd_rn(r[2], r[3]);
        const float s45 = __fadd_rn(r[4], r[5]);
        const float s67 = __fadd_rn(r[6], r[7]);
        z2s[p] = __fadd_rn(__fadd_rn(s01, s23), __fadd_rn(s45, s67));
    }
    __syncthreads();

    const int pg  = tid & 31;     // position group: p0..p0+3  (32 groups)
    const int cg  = tid >> 5;     // code group 0..15: codes k0..k0+7 per tile
    const int p0  = pg * 4;
    const int k0  = cg * 8;
    const int scg = cg & 3;       // swizzle key: 2 distinct cgs per wave
    const float* c2g = ws + WS_C2;

    float z2r[4];
    #pragma unroll
    for (int i = 0; i < 4; ++i) z2r[i] = z2s[p0 + i];

    float bestd[4] = {INFINITY, INFINITY, INFINITY, INFINITY};
    int   bestk[4] = {0, 0, 0, 0};

    const float4* t4 = (const float4*)tile;

    for (int t = 0; t < NTILES; ++t) {
        float a[4][8];
        #pragma unroll
        for (int i = 0; i < 4; ++i)
            #pragma unroll
            for (int j = 0; j < 8; ++j) a[i][j] = 0.0f;

        // 32 independent fma chains, each ascending c (reference order).
        // 12 ds_read_b128 per 128 FMAs per wave; z: lower/upper half broadcast
        // (free); codes: 2 distinct addrs/instr on distinct swizzled columns.
        #pragma unroll 2
        for (int c4 = 0; c4 < CDIM / 4; ++c4) {
            const int c = c4 * 4;
            const float4 zv0 = *(const float4*)&zt[c + 0][p0];
            const float4 zv1 = *(const float4*)&zt[c + 1][p0];
            const float4 zv2 = *(const float4*)&zt[c + 2][p0];
            const float4 zv3 = *(const float4*)&zt[c + 3][p0];
            const int col = c4 ^ scg;
            float4 cv[8];
            #pragma unroll
            for (int j = 0; j < 8; ++j) cv[j] = t4[((k0 + j) << 5) | col];
            #pragma unroll
            for (int j = 0; j < 8; ++j) {
                a[0][j] = fmaf(zv0.x, cv[j].x, a[0][j]);
                a[0][j] = fmaf(zv1.x, cv[j].y, a[0][j]);
                a[0][j] = fmaf(zv2.x, cv[j].z, a[0][j]);
                a[0][j] = fmaf(zv3.x, cv[j].w, a[0][j]);
                a[1][j] = fmaf(zv0.y, cv[j].x, a[1][j]);
                a[1][j] = fmaf(zv1.y, cv[j].y, a[1][j]);
                a[1][j] = fmaf(zv2.y, cv[j].z, a[1][j]);
                a[1][j] = fmaf(zv3.y, cv[j].w, a[1][j]);
                a[2][j] = fmaf(zv0.z, cv[j].x, a[2][j]);
                a[2][j] = fmaf(zv1.z, cv[j].y, a[2][j]);
                a[2][j] = fmaf(zv2.z, cv[j].z, a[2][j]);
                a[2][j] = fmaf(zv3.z, cv[j].w, a[2][j]);
                a[3][j] = fmaf(zv0.w, cv[j].x, a[3][j]);
                a[3][j] = fmaf(zv1.w, cv[j].y, a[3][j]);
                a[3][j] = fmaf(zv2.w, cv[j].z, a[3][j]);
                a[3][j] = fmaf(zv3.w, cv[j].w, a[3][j]);
            }
        }

        // d = fl(fl(z2 - 2*zc) + c2); strict < with ascending k (t, then j)
        const int kb = t * TK + k0;
        #pragma unroll
        for (int j = 0; j < 8; ++j) {
            const float c2 = c2g[kb + j];
            #pragma unroll
            for (int i = 0; i < 4; ++i) {
                const float d = __fadd_rn(fmaf(-2.0f, a[i][j], z2r[i]), c2);
                if (d < bestd[i]) { bestd[i] = d; bestk[i] = kb + j; }
            }
        }

        // ---- synchronous staging of tile t+1 (transient regs only) ---------
        if (t + 1 < NTILES) {
            __syncthreads();             // all waves done reading tile t
            const float4* src = (const float4*)(cb + (size_t)(t + 1) * TK * CDIM);
            float4* w4 = (float4*)tile;
            #pragma unroll
            for (int i = 0; i < (TK * CDIM / 4) / THREADS; ++i) {
                const int idx = i * THREADS + tid;
                const int k = idx >> 5;
                const int f = idx & 31;
                w4[(k << 5) | (f ^ ((k >> 3) & 3))] = src[idx];
            }
            __syncthreads();
        }
    }

    #pragma unroll
    for (int i = 0; i < 4; ++i) {
        bdls[cg][p0 + i] = bestd[i];
        bkls[cg][p0 + i] = bestk[i];
    }
    __syncthreads();

    // ---- combine 16 disjoint code-subsets per position; lexicographic (d,k)
    unsigned int* ghist = (unsigned int*)ws + WS_HIST;
    if (tid < P) {
        const int p = tid;
        float bd = bdls[0][p];
        int   bk = bkls[0][p];
        #pragma unroll
        for (int g = 1; g < 16; ++g) {
            const float d = bdls[g][p];
            const int   k = bkls[g][p];
            if (d < bd || (d == bd && k < bk)) { bd = d; bk = k; }
        }
        wkls[p] = bk;
        out[IDX_OFF + (size_t)(nbase + p)] = (float)bk;
        atomicAdd(&ghist[bk], 1u);       // 128/block, 1024 bins: low contention
        red[tid] = bd;     // best_d == fl(||z-q||^2), loss has 2% slack
    } else {
        red[tid] = 0.0f;
    }
    __syncthreads();
    for (int s = THREADS / 2; s > 0; s >>= 1) {
        if (tid < s) red[tid] += red[tid + s];
        __syncthreads();
    }
    if (tid == 0) atomicAdd(&ws[WS_LOSS], red[0]);

    // ---- quantized output: out[b][c][hw0+p] = cb[wk[p]][c] -----------------
    // stores coalesced (512B per c-row); cb gather L1/L2-hot.
    float* ob = out + (size_t)b * CDIM * HWSZ + hw0;
    #pragma unroll
    for (int i = 0; i < (CDIM * P) / THREADS; ++i) {   // 32 iters
        const int linear = i * THREADS + tid;          // 0..16383
        const int c = linear >> 7;
        const int p = linear & 127;
        ob[(size_t)c * HWSZ + p] = cb[(size_t)wkls[p] * CDIM + c];
    }
}

// ---- pass 2: scalars --------------------------------------------------------
__global__ __launch_bounds__(1024) void vq_final(const float* __restrict__ ws,
                                                 float* __restrict__ out) {
    __shared__ float red[1024];
    const int t = threadIdx.x;
    const unsigned int* hist = (const unsigned int*)ws + WS_HIST;
    const float p = (float)hist[t] * INV_NPOS;
    red[t] = p * logf(p + 1e-10f);
    __syncthreads();
    for (int s = 512; s > 0; s >>= 1) {
        if (t < s) red[t] += red[t + s];
        __syncthreads();
    }
    if (t == 0) {
        out[LOSS_OFF] = 1.25f * (ws[WS_LOSS] * INV_TOTAL);   // cb + 0.25*commit
        out[PERP_OFF] = expf(-red[0]);
    }
}

extern "C" void kernel_launch(void* const* d_in, const int* in_sizes, int n_in,
                              void* d_out, int out_size, void* d_ws, size_t ws_size,
                              hipStream_t stream) {
    const float* z  = (const float*)d_in[0];
    const float* cb = (const float*)d_in[1];
    float* out = (float*)d_out;
    float* ws  = (float*)d_ws;

    vq_prep <<<KCODES / 256, 256, 0, stream>>>(cb, ws);
    vq_main <<<NPOS / P,     THREADS, 0, stream>>>(z, cb, ws, out);
    vq_final<<<1,           1024, 0, stream>>>(ws, out);
}